// Round 1
// baseline (3620.045 us; speedup 1.0000x reference)
//
#include <hip/hip_runtime.h>
#include <math.h>

// Problem constants (from reference setup_inputs)
#define HO 512
#define WO 512
#define HI 128
#define WI 128
#define CC 64      // channels C
#define BS 2       // batch
#define PPB 32     // pixels per block (one row segment; 512 % 32 == 0)
#define NT 256     // threads per block

// Fused kernel: per 32-pixel tile
//   stage 1: h1 = relu(W1 @ p + b1)        [32 x 64]   (LDS)
//   stage 2: h2 = relu(W2 @ h1 + b2)       [32 x 256]  (LDS)
//   stage 3: w  = W3 @ h2 + b3 (per channel: 9 taps), softmax over taps,
//            gather 3x3 patch of x at (interMapY, interMapX) with zero pad,
//            weighted sum -> out[b,c,y,x]
__global__ __launch_bounds__(NT, 2)
void bilinear_upsampler_fused(const float* __restrict__ x,
                              const float* __restrict__ poseMap,
                              const float* __restrict__ W1, const float* __restrict__ b1,
                              const float* __restrict__ W2, const float* __restrict__ b2,
                              const float* __restrict__ W3, const float* __restrict__ b3,
                              const int* __restrict__ iY, const int* __restrict__ iX,
                              float* __restrict__ out)
{
    __shared__ float sP[3][PPB];
    __shared__ int   sIY[PPB];
    __shared__ int   sIX[PPB];
    __shared__ float sH1[PPB][65];    // stride 65 breaks bank alignment
    __shared__ float sH2[PPB][257];   // stride 257

    const int t = threadIdx.x;
    const int pixBase = blockIdx.x * PPB;   // all PPB pixels share row y
    const int y  = pixBase / WO;
    const int x0 = pixBase % WO;

    // --- load pose values + index maps for this tile ---
    if (t < 96) {
        int ch = t >> 5, p = t & 31;
        sP[ch][p] = poseMap[ch * (HO * WO) + pixBase + p];
    } else if (t < 128) {
        int p = t & 31;
        sIY[p] = iY[pixBase + p];
    } else if (t < 160) {
        int p = t & 31;
        sIX[p] = iX[pixBase + p];
    }
    __syncthreads();

    // --- stage 1: h1[p][o] = relu(sum_i W1[o,i]*p_i + b1[o]), o<64 ---
    #pragma unroll
    for (int r = 0; r < 8; ++r) {
        int idx = t + r * NT;        // 0..2047
        int p = idx & 31;
        int o = idx >> 5;            // 0..63
        float a = b1[o];
        a = fmaf(W1[o * 3 + 0], sP[0][p], a);
        a = fmaf(W1[o * 3 + 1], sP[1][p], a);
        a = fmaf(W1[o * 3 + 2], sP[2][p], a);
        sH1[p][o] = fmaxf(a, 0.f);
    }
    __syncthreads();

    // --- stage 2: h2[p][o] = relu(sum_i W2[o,i]*h1[p][i] + b2[o]), o<256 ---
    {
        const int pg = t & 7;        // pixel group: pixels pg*4 .. pg*4+3
        const int og = t >> 3;       // 0..31 -> outputs og*8 .. og*8+7
        float acc[4][8];
        #pragma unroll
        for (int jo = 0; jo < 8; ++jo) {
            float bv = b2[og * 8 + jo];
            #pragma unroll
            for (int j = 0; j < 4; ++j) acc[j][jo] = bv;
        }
        for (int i = 0; i < 64; ++i) {
            float hv[4];
            #pragma unroll
            for (int j = 0; j < 4; ++j) hv[j] = sH1[pg * 4 + j][i];
            float wv[8];
            #pragma unroll
            for (int jo = 0; jo < 8; ++jo) wv[jo] = W2[(og * 8 + jo) * 64 + i];
            #pragma unroll
            for (int j = 0; j < 4; ++j)
                #pragma unroll
                for (int jo = 0; jo < 8; ++jo)
                    acc[j][jo] = fmaf(hv[j], wv[jo], acc[j][jo]);
        }
        #pragma unroll
        for (int j = 0; j < 4; ++j)
            #pragma unroll
            for (int jo = 0; jo < 8; ++jo)
                sH2[pg * 4 + j][og * 8 + jo] = fmaxf(acc[j][jo], 0.f);
    }
    __syncthreads();

    // --- stage 3: per (channel, pixel): 9 logits -> softmax -> gather/output ---
    const int pg = t & 7;            // pixels pg*4 .. pg*4+3
    const int cl = t >> 3;           // 0..31
    #pragma unroll
    for (int pass = 0; pass < 2; ++pass) {
        const int c = pass * 32 + cl;
        float acc[4][9];
        #pragma unroll
        for (int jj = 0; jj < 9; ++jj) {
            float bv = b3[c * 9 + jj];
            #pragma unroll
            for (int j = 0; j < 4; ++j) acc[j][jj] = bv;
        }
        const float* __restrict__ w3r = W3 + c * 9 * 256;
        #pragma unroll 2
        for (int k = 0; k < 256; ++k) {
            float hv[4];
            #pragma unroll
            for (int j = 0; j < 4; ++j) hv[j] = sH2[pg * 4 + j][k];
            float wv[9];
            #pragma unroll
            for (int jj = 0; jj < 9; ++jj) wv[jj] = w3r[jj * 256 + k];
            #pragma unroll
            for (int j = 0; j < 4; ++j)
                #pragma unroll
                for (int jj = 0; jj < 9; ++jj)
                    acc[j][jj] = fmaf(hv[j], wv[jj], acc[j][jj]);
        }
        // epilogue: softmax over taps, gather, store
        #pragma unroll
        for (int j = 0; j < 4; ++j) {
            const int p = pg * 4 + j;
            float m = acc[j][0];
            #pragma unroll
            for (int jj = 1; jj < 9; ++jj) m = fmaxf(m, acc[j][jj]);
            float sw[9];
            float s = 0.f;
            #pragma unroll
            for (int jj = 0; jj < 9; ++jj) { sw[jj] = __expf(acc[j][jj] - m); s += sw[jj]; }
            const float inv = 1.f / s;
            const int iy = sIY[p];
            const int ix = sIX[p];
            #pragma unroll
            for (int b = 0; b < BS; ++b) {
                const float* __restrict__ xp = x + (size_t)(b * CC + c) * (HI * WI);
                float o = 0.f;
                #pragma unroll
                for (int jj = 0; jj < 9; ++jj) {
                    const int ys = iy + (jj / 3) - 1;
                    const int xs = ix + (jj % 3) - 1;
                    float xv = (ys >= 0 && ys < HI && xs >= 0 && xs < WI)
                                   ? xp[ys * WI + xs] : 0.f;
                    o = fmaf(sw[jj] * inv, xv, o);
                }
                out[(((size_t)(b * CC + c) * HO) + y) * WO + x0 + p] = o;
            }
        }
    }
}

extern "C" void kernel_launch(void* const* d_in, const int* in_sizes, int n_in,
                              void* d_out, int out_size, void* d_ws, size_t ws_size,
                              hipStream_t stream) {
    const float* x    = (const float*)d_in[0];
    const float* pose = (const float*)d_in[1];
    const float* W1   = (const float*)d_in[2];
    const float* b1   = (const float*)d_in[3];
    const float* W2   = (const float*)d_in[4];
    const float* b2   = (const float*)d_in[5];
    const float* W3   = (const float*)d_in[6];
    const float* b3   = (const float*)d_in[7];
    const int*   iY   = (const int*)d_in[8];
    const int*   iX   = (const int*)d_in[9];
    float* out = (float*)d_out;

    const int nblocks = (HO * WO) / PPB;   // 8192
    bilinear_upsampler_fused<<<nblocks, NT, 0, stream>>>(
        x, pose, W1, b1, W2, b2, W3, b3, iY, iX, out);
}

// Round 3
// 945.821 us; speedup vs baseline: 3.8274x; 3.8274x over previous
//
#include <hip/hip_runtime.h>
#include <math.h>

// Problem constants
#define HO 512
#define WO 512
#define HI 128
#define WI 128
#define CC 64      // channels
#define BS 2       // batch
#define NPX 64     // pixels per block (one row segment)
#define NT 256     // threads per block

// Packed weight sizes (bf16 elements) in d_ws:
//   w2p: [nt=16][ks=2][lane=64][j=8]  = 16384
//   w3p: [ntg=36][ks=8][lane=64][j=8] = 147456
#define W2P_ELEMS (16 * 2 * 64 * 8)
#define W3P_ELEMS (36 * 8 * 64 * 8)

typedef __attribute__((ext_vector_type(8))) short short8;
typedef __attribute__((ext_vector_type(4))) float float4v;

__device__ __forceinline__ unsigned short f2bf(float f) {
    unsigned u = __builtin_bit_cast(unsigned, f);
    unsigned r = (u + 0x7FFFu + ((u >> 16) & 1u)) >> 16;   // RNE
    return (unsigned short)r;
}
__device__ __forceinline__ float bf2f(unsigned short b) {
    unsigned u = ((unsigned)b) << 16;
    return __builtin_bit_cast(float, u);
}

// ---------------- prepack: W2 / W3 -> bf16 MFMA B-fragment order ----------------
// B-fragment (16x16x32): lane l holds B[n = l&15][k = (l>>4)*8 + j], j=0..7
__global__ void prepack_weights(const float* __restrict__ W2,
                                const float* __restrict__ W3,
                                unsigned short* __restrict__ wsp) {
    int idx = blockIdx.x * blockDim.x + threadIdx.x;
    const int total = W2P_ELEMS + W3P_ELEMS;
    for (; idx < total; idx += gridDim.x * blockDim.x) {
        float v;
        if (idx < W2P_ELEMS) {
            int j = idx & 7, lane = (idx >> 3) & 63, rest = idx >> 9;
            int ks = rest & 1, nt = rest >> 1;
            int n = nt * 16 + (lane & 15);
            int k = ks * 32 + (lane >> 4) * 8 + j;
            v = W2[n * 64 + k];          // W2 is [256][64] = [n][k]
        } else {
            int i2 = idx - W2P_ELEMS;
            int j = i2 & 7, lane = (i2 >> 3) & 63, rest = i2 >> 9;
            int ks = rest & 7, nt = rest >> 3;
            int n = nt * 16 + (lane & 15);
            int k = ks * 32 + (lane >> 4) * 8 + j;
            v = W3[n * 256 + k];         // W3 is [576][256] = [n][k]
        }
        wsp[idx] = f2bf(v);
    }
}

// ---------------- fused main kernel ----------------
// Per block: 64 pixels (one row segment), 4 waves, wave owns 16 pixels.
// stage1 (VALU):  h1[64][64]  -> LDS bf16
// stage2 (MFMA):  h2[64][256] -> LDS bf16
// stage3 (MFMA):  logits 576 per pixel, in 4 chunks of 144 -> LDS bf16 ->
//                 softmax over 9 taps -> gather x 3x3 -> out
__global__ __launch_bounds__(NT, 2)
void fused_main(const float* __restrict__ x, const float* __restrict__ pose,
                const float* __restrict__ W1, const float* __restrict__ b1,
                const float* __restrict__ b2, const float* __restrict__ b3,
                const int* __restrict__ iY, const int* __restrict__ iX,
                const unsigned short* __restrict__ wsp,
                float* __restrict__ out)
{
    // strides padded to 16B multiples; A-frag ds_read_b128 lands 2-way bank
    // aliased at worst (free per m136)
    __shared__ unsigned short sH1[NPX][72];    // 9.2 KB  (stride 144 B)
    __shared__ unsigned short sH2[NPX][264];   // 33.8 KB (stride 528 B)
    __shared__ unsigned short sLG[NPX][160];   // 20.5 KB (ch*10+tap layout)
    __shared__ float sP[3][NPX];
    __shared__ int sIY[NPX], sIX[NPX];

    const int t = threadIdx.x;
    const int pixBase = blockIdx.x * NPX;    // 64 px within one output row
    const int y  = pixBase / WO;
    const int x0 = pixBase % WO;

    if (t < 192) sP[t >> 6][t & 63] = pose[(t >> 6) * (HO * WO) + pixBase + (t & 63)];
    if (t < 64) sIY[t] = iY[pixBase + t];
    else if (t < 128) sIX[t - 64] = iX[pixBase + t - 64];
    __syncthreads();

    // ---- stage 1: h1 = relu(W1 @ p + b1), each thread: 16 outputs of 1 pixel
    {
        const int p  = t & 63;
        const int og = t >> 6;               // this wave writes cols og*16..+15
        const float p0 = sP[0][p], p1 = sP[1][p], p2 = sP[2][p];
        #pragma unroll
        for (int i = 0; i < 16; i += 2) {
            const int o = og * 16 + i;
            float a0 = fmaf(W1[o * 3 + 2], p2, fmaf(W1[o * 3 + 1], p1, fmaf(W1[o * 3 + 0], p0, b1[o])));
            float a1 = fmaf(W1[o * 3 + 5], p2, fmaf(W1[o * 3 + 4], p1, fmaf(W1[o * 3 + 3], p0, b1[o + 1])));
            a0 = fmaxf(a0, 0.f); a1 = fmaxf(a1, 0.f);
            unsigned pack = (unsigned)f2bf(a0) | ((unsigned)f2bf(a1) << 16);
            *(unsigned*)&sH1[p][o] = pack;
        }
    }
    __syncthreads();

    const int wv = t >> 6, l = t & 63, lm = l & 15, lq = l >> 4;
    const int m0 = wv * 16;                  // wave's pixel base

    // ---- stage 2: h2 = relu(h1 @ W2^T + b2)  [16px x 256] per wave
    {
        // A-frag: lane holds A[m=lm][k=lq*8+j]
        short8 a0 = *(const short8*)&sH1[m0 + lm][0  + lq * 8];
        short8 a1 = *(const short8*)&sH1[m0 + lm][32 + lq * 8];
        const short8* w2f = (const short8*)wsp;
        #pragma unroll 4
        for (int nt = 0; nt < 16; ++nt) {
            float4v acc = {0.f, 0.f, 0.f, 0.f};
            short8 bf0 = w2f[(nt * 2 + 0) * 64 + l];
            short8 bf1 = w2f[(nt * 2 + 1) * 64 + l];
            acc = __builtin_amdgcn_mfma_f32_16x16x32_bf16(a0, bf0, acc, 0, 0, 0);
            acc = __builtin_amdgcn_mfma_f32_16x16x32_bf16(a1, bf1, acc, 0, 0, 0);
            const float bv = b2[nt * 16 + lm];
            #pragma unroll
            for (int r = 0; r < 4; ++r) {
                // D[m=lq*4+r][n=lm] (+ nt*16)
                float h = fmaxf(acc[r] + bv, 0.f);
                sH2[m0 + lq * 4 + r][nt * 16 + lm] = f2bf(h);
            }
        }
    }
    __syncthreads();

    const int iy = sIY[m0 + lm];
    const int ix = sIX[m0 + lm];
    const short8* w3f = (const short8*)(wsp + W2P_ELEMS);

    // ---- stage 3: 4 chunks of 144 logits (16 channels x 9 taps)
    for (int chunk = 0; chunk < 4; ++chunk) {
        float4v accs[9];
        #pragma unroll
        for (int tn = 0; tn < 9; ++tn) accs[tn] = (float4v){0.f, 0.f, 0.f, 0.f};

        #pragma unroll 2
        for (int ks = 0; ks < 8; ++ks) {
            short8 a = *(const short8*)&sH2[m0 + lm][ks * 32 + lq * 8];
            #pragma unroll
            for (int tn = 0; tn < 9; ++tn) {
                const int ntg = chunk * 9 + tn;
                short8 b = w3f[(ntg * 8 + ks) * 64 + l];
                accs[tn] = __builtin_amdgcn_mfma_f32_16x16x32_bf16(a, b, accs[tn], 0, 0, 0);
            }
        }

        // bias + write logits (bf16) to per-wave rows of sLG; layout [px][ch*10+tap]
        #pragma unroll
        for (int tn = 0; tn < 9; ++tn) {
            const int nl = tn * 16 + lm;             // 0..143
            const float bv = b3[chunk * 144 + nl];
            const int lch = (nl * 456) >> 12;        // floor(nl/9), exact for nl<144
            const int tap = nl - lch * 9;
            #pragma unroll
            for (int r = 0; r < 4; ++r) {
                float v = accs[tn][r] + bv;
                sLG[m0 + lq * 4 + r][lch * 10 + tap] = f2bf(v);
            }
        }
        // Cross-lane handoff through LDS: MUST synchronize before reading data
        // written by other lanes (compiler may otherwise hoist the ds_reads
        // above the ds_writes — per-thread they don't alias). R2's NaN bug.
        __syncthreads();

        // softmax + gather + store: 16px x 16ch per wave = 4 items/lane
        #pragma unroll
        for (int it = 0; it < 4; ++it) {
            const int p   = lm;
            const int lch = lq * 4 + it;
            const int c   = chunk * 16 + lch;
            const unsigned short* lg = &sLG[m0 + p][lch * 10];  // 4B-aligned
            const unsigned* lg32 = (const unsigned*)lg;
            float lv[9];
            #pragma unroll
            for (int q2 = 0; q2 < 4; ++q2) {
                const unsigned u = lg32[q2];
                lv[q2 * 2]     = __builtin_bit_cast(float, u << 16);
                lv[q2 * 2 + 1] = __builtin_bit_cast(float, u & 0xFFFF0000u);
            }
            lv[8] = bf2f(lg[8]);

            float mx = lv[0];
            #pragma unroll
            for (int k2 = 1; k2 < 9; ++k2) mx = fmaxf(mx, lv[k2]);
            float wn[9];
            float s = 0.f;
            #pragma unroll
            for (int k2 = 0; k2 < 9; ++k2) { wn[k2] = __expf(lv[k2] - mx); s += wn[k2]; }
            const float inv = 1.f / s;
            #pragma unroll
            for (int k2 = 0; k2 < 9; ++k2) wn[k2] *= inv;

            const int xg = x0 + m0 + p;
            #pragma unroll
            for (int b = 0; b < BS; ++b) {
                const float* __restrict__ xp = x + (size_t)(b * CC + c) * (HI * WI);
                float o = 0.f;
                #pragma unroll
                for (int k2 = 0; k2 < 9; ++k2) {
                    const int ys = iy + k2 / 3 - 1;
                    const int xs = ix + k2 % 3 - 1;
                    const float xv = (ys >= 0 && ys < HI && xs >= 0 && xs < WI)
                                         ? xp[ys * WI + xs] : 0.f;
                    o = fmaf(wn[k2], xv, o);
                }
                out[((size_t)(b * CC + c) * HO + y) * WO + xg] = o;
            }
        }
        // next chunk's sLG writes are WAR-safe: rows are wave-private and the
        // barrier above already ordered this chunk's reads for all waves
    }
}

extern "C" void kernel_launch(void* const* d_in, const int* in_sizes, int n_in,
                              void* d_out, int out_size, void* d_ws, size_t ws_size,
                              hipStream_t stream) {
    const float* x    = (const float*)d_in[0];
    const float* pose = (const float*)d_in[1];
    const float* W1   = (const float*)d_in[2];
    const float* b1   = (const float*)d_in[3];
    const float* W2   = (const float*)d_in[4];
    const float* b2   = (const float*)d_in[5];
    const float* W3   = (const float*)d_in[6];
    const float* b3   = (const float*)d_in[7];
    const int*   iY   = (const int*)d_in[8];
    const int*   iX   = (const int*)d_in[9];
    float* out = (float*)d_out;
    unsigned short* wsp = (unsigned short*)d_ws;

    prepack_weights<<<64, NT, 0, stream>>>(W2, W3, wsp);

    const int nblocks = (HO * WO) / NPX;   // 4096
    fused_main<<<nblocks, NT, 0, stream>>>(
        x, pose, W1, b1, b2, b3, iY, iX, wsp, out);
}

// Round 4
// 424.985 us; speedup vs baseline: 8.5181x; 2.2255x over previous
//
#include <hip/hip_runtime.h>
#include <math.h>

// Problem constants
#define HO 512
#define WO 512
#define HI 128
#define WI 128
#define CC 64      // channels
#define BS 2       // batch
#define NPX 64     // pixels per block (one row segment)
#define NT 256     // threads per block

// d_ws layout:
//   [0)              bf16 packed weights: w2p then w3p
//   [XT_BYTE_OFF)    x_t padded transpose: float [130][130][2][64]
#define W2P_ELEMS (16 * 2 * 64 * 8)      // [nt=16][ks=2][lane=64][j=8]
#define W3P_ELEMS (36 * 8 * 64 * 8)      // [nt=36][ks=8][lane=64][j=8], nt = tap*4+chtile
#define XT_ELEM_OFF (W2P_ELEMS + W3P_ELEMS)     // in shorts (163840 -> 327680 B, 16B aligned)
#define XT_FLOATS (130 * 130 * 128)             // 2,163,200 floats = 8.65 MB

typedef __attribute__((ext_vector_type(8))) short short8;
typedef __attribute__((ext_vector_type(4))) float float4v;

__device__ __forceinline__ unsigned short f2bf(float f) {
    unsigned u = __builtin_bit_cast(unsigned, f);
    unsigned r = (u + 0x7FFFu + ((u >> 16) & 1u)) >> 16;   // RNE
    return (unsigned short)r;
}

// ---------------- k1: pack weights to MFMA-B order + zero x_t ----------------
// B-frag (16x16x32): lane l holds B[n=l&15][k=(l>>4)*8+j], j=0..7
// W3 n-tile nt = tap*4 + chtile: covers W3 rows (chtile*16 + (l&15))*9 + tap
__global__ void prepack_zw(const float* __restrict__ W2,
                           const float* __restrict__ W3,
                           unsigned short* __restrict__ wsp,
                           float* __restrict__ xt) {
    const int total = W2P_ELEMS + W3P_ELEMS;
    for (int idx = blockIdx.x * blockDim.x + threadIdx.x; idx < total;
         idx += gridDim.x * blockDim.x) {
        float v;
        if (idx < W2P_ELEMS) {
            int j = idx & 7, lane = (idx >> 3) & 63, rest = idx >> 9;
            int ks = rest & 1, nt = rest >> 1;
            int n = nt * 16 + (lane & 15);
            int k = ks * 32 + (lane >> 4) * 8 + j;
            v = W2[n * 64 + k];                      // W2: [256][64]
        } else {
            int i2 = idx - W2P_ELEMS;
            int j = i2 & 7, lane = (i2 >> 3) & 63, rest = i2 >> 9;
            int ks = rest & 7, nt = rest >> 3;       // nt = tap*4+chtile
            int tap = nt >> 2, ct = nt & 3;
            int row = (ct * 16 + (lane & 15)) * 9 + tap;   // < 576
            int k = ks * 32 + (lane >> 4) * 8 + j;
            v = W3[row * 256 + k];                   // W3: [576][256]
        }
        wsp[idx] = f2bf(v);
    }
    // zero x_t (borders stay zero; interior overwritten by prepack_x)
    float4v z = {0.f, 0.f, 0.f, 0.f};
    float4v* xt4 = (float4v*)xt;
    for (int i = blockIdx.x * blockDim.x + threadIdx.x; i < XT_FLOATS / 4;
         i += gridDim.x * blockDim.x)
        xt4[i] = z;
}

// ---------------- k2: x -> x_t[(h+1)][(w+1)][b][c] (interior) ----------------
// 262144 threads; lanes consecutive = consecutive w -> coalesced reads.
__global__ void prepack_x(const float* __restrict__ x, float* __restrict__ xt) {
    const int tid = blockIdx.x * blockDim.x + threadIdx.x;
    const int pos = tid & 16383;          // h*128+w
    const int g   = tid >> 14;            // bc group: 8 channels
    const int h = pos >> 7, w = pos & 127;
    const float* src = x + pos;
    float4v v0, v1;
    #pragma unroll
    for (int j = 0; j < 4; ++j) v0[j] = src[(size_t)(g * 8 + j) * (HI * WI)];
    #pragma unroll
    for (int j = 0; j < 4; ++j) v1[j] = src[(size_t)(g * 8 + 4 + j) * (HI * WI)];
    float* dst = xt + ((h + 1) * 130 + (w + 1)) * 128 + g * 8;
    *(float4v*)dst = v0;
    *(float4v*)(dst + 4) = v1;
}

// ---------------- fused main kernel ----------------
// Per block: 64 pixels (one row segment), 4 waves x 16 pixels.
// stage1 (VALU): h1[64][64] -> LDS bf16
// stage2 (MFMA): h2[64][256] -> LDS bf16
// stage3 (MFMA): per chtile (16 ch): 9 tap-logits per (ch,px) land in REGISTERS
//                -> softmax in regs -> coalesced gather from x_t -> LDS out
//                transpose -> coalesced store
__global__ __launch_bounds__(NT, 3)
void fused_main(const float* __restrict__ xt, const float* __restrict__ pose,
                const float* __restrict__ W1, const float* __restrict__ b1,
                const float* __restrict__ b2, const float* __restrict__ b3,
                const int* __restrict__ iY, const int* __restrict__ iX,
                const unsigned short* __restrict__ wsp,
                float* __restrict__ out)
{
    // Manual LDS layout (52.5 KB -> 3 blocks/CU). sH1 dead after stage2;
    // overlap it with the double-buffered sOut transpose tile.
    __shared__ char smem[33792 + 17408 + 768 + 512];
    unsigned short (*sH2)[264] = (unsigned short (*)[264])&smem[0];        // 33792 B
    unsigned short (*sH1)[72]  = (unsigned short (*)[72])&smem[33792];     // 9216 B (union)
    float (*sOut)[2][16][68]   = (float (*)[2][16][68])&smem[33792];       // 2x8704 B (union)
    float (*sP)[NPX]           = (float (*)[NPX])&smem[51200];             // 768 B
    int* sIY                   = (int*)&smem[51968];                       // 256 B
    int* sIX                   = (int*)&smem[52224];                       // 256 B

    const int t = threadIdx.x;
    const int pixBase = blockIdx.x * NPX;    // 64 px within one output row
    const int y  = pixBase / WO;
    const int x0 = pixBase % WO;

    if (t < 192) sP[t >> 6][t & 63] = pose[(t >> 6) * (HO * WO) + pixBase + (t & 63)];
    if (t < 64) sIY[t] = iY[pixBase + t];
    else if (t < 128) sIX[t - 64] = iX[pixBase + t - 64];
    __syncthreads();

    // ---- stage 1: h1 = relu(W1 @ p + b1)
    {
        const int p  = t & 63;
        const int og = t >> 6;
        const float p0 = sP[0][p], p1 = sP[1][p], p2 = sP[2][p];
        #pragma unroll
        for (int i = 0; i < 16; i += 2) {
            const int o = og * 16 + i;
            float a0 = fmaf(W1[o * 3 + 2], p2, fmaf(W1[o * 3 + 1], p1, fmaf(W1[o * 3 + 0], p0, b1[o])));
            float a1 = fmaf(W1[o * 3 + 5], p2, fmaf(W1[o * 3 + 4], p1, fmaf(W1[o * 3 + 3], p0, b1[o + 1])));
            a0 = fmaxf(a0, 0.f); a1 = fmaxf(a1, 0.f);
            unsigned pack = (unsigned)f2bf(a0) | ((unsigned)f2bf(a1) << 16);
            *(unsigned*)&sH1[p][o] = pack;
        }
    }
    __syncthreads();

    const int wv = t >> 6, l = t & 63, lm = l & 15, lq = l >> 4;
    const int m0 = wv * 16;                  // wave's pixel base

    // ---- stage 2: h2 = relu(h1 @ W2^T + b2)  [16px x 256] per wave
    {
        short8 a0 = *(const short8*)&sH1[m0 + lm][0  + lq * 8];
        short8 a1 = *(const short8*)&sH1[m0 + lm][32 + lq * 8];
        const short8* w2f = (const short8*)wsp;
        #pragma unroll 4
        for (int nt = 0; nt < 16; ++nt) {
            float4v acc = {0.f, 0.f, 0.f, 0.f};
            short8 bf0 = w2f[(nt * 2 + 0) * 64 + l];
            short8 bf1 = w2f[(nt * 2 + 1) * 64 + l];
            acc = __builtin_amdgcn_mfma_f32_16x16x32_bf16(a0, bf0, acc, 0, 0, 0);
            acc = __builtin_amdgcn_mfma_f32_16x16x32_bf16(a1, bf1, acc, 0, 0, 0);
            const float bv = b2[nt * 16 + lm];
            #pragma unroll
            for (int r = 0; r < 4; ++r)
                sH2[m0 + lq * 4 + r][nt * 16 + lm] = f2bf(fmaxf(acc[r] + bv, 0.f));
        }
    }
    __syncthreads();   // sH1 also dead beyond this point (sOut may overwrite)

    // per-lane pixel bases into x_t (pixels p = m0 + lq*4 + r)
    int pbase[4];
    #pragma unroll
    for (int r = 0; r < 4; ++r) {
        const int p = m0 + lq * 4 + r;
        pbase[r] = ((sIY[p] + 1) * 130 + (sIX[p] + 1)) * 128;
    }
    const int koff[9] = {-131 * 128, -130 * 128, -129 * 128,
                         -1 * 128,   0,          1 * 128,
                         129 * 128,  130 * 128,  131 * 128};
    const short8* w3f = (const short8*)(wsp + W2P_ELEMS);

    // ---- stage 3: 4 chtiles of 16 channels; 9 taps in registers
    for (int ct = 0; ct < 4; ++ct) {
        float4v accs[9];
        #pragma unroll
        for (int tap = 0; tap < 9; ++tap) accs[tap] = (float4v){0.f, 0.f, 0.f, 0.f};

        #pragma unroll 2
        for (int ks = 0; ks < 8; ++ks) {
            short8 a = *(const short8*)&sH2[m0 + lm][ks * 32 + lq * 8];
            #pragma unroll
            for (int tap = 0; tap < 9; ++tap) {
                short8 b = w3f[(((tap << 2) | ct) * 8 + ks) * 64 + l];
                accs[tap] = __builtin_amdgcn_mfma_f32_16x16x32_bf16(a, b, accs[tap], 0, 0, 0);
            }
        }

        const int c = ct * 16 + lm;          // this lane's channel
        float bv[9];
        #pragma unroll
        for (int tap = 0; tap < 9; ++tap) bv[tap] = b3[c * 9 + tap];

        float ob0[4], ob1[4];
        #pragma unroll
        for (int r = 0; r < 4; ++r) {
            float lg[9];
            #pragma unroll
            for (int tap = 0; tap < 9; ++tap) lg[tap] = accs[tap][r] + bv[tap];
            float mx = lg[0];
            #pragma unroll
            for (int tap = 1; tap < 9; ++tap) mx = fmaxf(mx, lg[tap]);
            const float* xb = xt + pbase[r] + c;
            float s = 0.f, o0 = 0.f, o1 = 0.f;
            #pragma unroll
            for (int tap = 0; tap < 9; ++tap) {
                const float ev = __expf(lg[tap] - mx);
                s += ev;
                o0 = fmaf(ev, xb[koff[tap]], o0);        // b=0, coalesced over lm
                o1 = fmaf(ev, xb[koff[tap] + 64], o1);   // b=1
            }
            const float inv = 1.f / s;
            ob0[r] = o0 * inv;
            ob1[r] = o1 * inv;
        }

        // transpose via LDS (double-buffered) -> coalesced stores
        float (*so)[16][68] = sOut[ct & 1];
        *(float4v*)&so[0][lm][m0 + lq * 4] = (float4v){ob0[0], ob0[1], ob0[2], ob0[3]};
        *(float4v*)&so[1][lm][m0 + lq * 4] = (float4v){ob1[0], ob1[1], ob1[2], ob1[3]};
        __syncthreads();   // cross-lane handoff (R2 lesson: never skip)

        const int row = t >> 3;              // 0..31 = (b,ch16)
        const int b   = row >> 4, ch = row & 15;
        const int seg = (t & 7) * 8;
        float4v v0 = *(float4v*)&so[b][ch][seg];
        float4v v1 = *(float4v*)&so[b][ch][seg + 4];
        float* op = out + (((size_t)(b * CC + ct * 16 + ch) * HO) + y) * WO + x0 + seg;
        *(float4v*)op = v0;
        *(float4v*)(op + 4) = v1;
        // next ct writes the other sOut buffer -> no WAR barrier needed
    }
}

extern "C" void kernel_launch(void* const* d_in, const int* in_sizes, int n_in,
                              void* d_out, int out_size, void* d_ws, size_t ws_size,
                              hipStream_t stream) {
    const float* x    = (const float*)d_in[0];
    const float* pose = (const float*)d_in[1];
    const float* W1   = (const float*)d_in[2];
    const float* b1   = (const float*)d_in[3];
    const float* W2   = (const float*)d_in[4];
    const float* b2   = (const float*)d_in[5];
    const float* W3   = (const float*)d_in[6];
    const float* b3   = (const float*)d_in[7];
    const int*   iY   = (const int*)d_in[8];
    const int*   iX   = (const int*)d_in[9];
    float* out = (float*)d_out;
    unsigned short* wsp = (unsigned short*)d_ws;
    float* xt = (float*)((char*)d_ws + XT_ELEM_OFF * sizeof(unsigned short));

    prepack_zw<<<2048, NT, 0, stream>>>(W2, W3, wsp, xt);
    prepack_x<<<1024, NT, 0, stream>>>(x, xt);

    const int nblocks = (HO * WO) / NPX;   // 4096
    fused_main<<<nblocks, NT, 0, stream>>>(
        xt, pose, W1, b1, b2, b3, iY, iX, wsp, out);
}